// Round 15
// baseline (113.203 us; speedup 1.0000x reference)
//
#include <hip/hip_runtime.h>
#include <stdint.h>
#include <math.h>

#define NROWS 8192
#define DDIM  256
#define BM    128
#define BN    128
#define GJ    8                         // column groups (grid.y)
#define COLS_PER_GROUP (NROWS / GJ)     // 1024

constexpr float INV_T  = 1.0f / 0.07f;  // fixed LSE max M0 = 1/T (|logit| <= 1/T)
constexpr float LOG2E  = 1.44269504f;
constexpr float K1     = INV_T * LOG2E; // exp2 arg: fma(acc, K1, -K1)

typedef __bf16 bf16x8 __attribute__((ext_vector_type(8)));
typedef float  f32x16 __attribute__((ext_vector_type(16)));

__device__ __forceinline__ void async_copy16(const uint16_t* g, uint16_t* l) {
    __builtin_amdgcn_global_load_lds(
        (const __attribute__((address_space(1))) uint32_t*)g,
        (__attribute__((address_space(3))) uint32_t*)l, 16, 0, 0);
}

__device__ inline uint16_t f2bf(float f) {
    uint32_t u = __float_as_uint(f);
    u += 0x7fffu + ((u >> 16) & 1u);    // RNE
    return (uint16_t)(u >> 16);
}

// Kernel 1: normalize rows to unit length (bf16 out). One wave per row.
// q-row waves ALSO compute l_pos = cos(q_i,k_i) in fp32 (validated rounds 6-14):
// LSE over [l_pos, row-with-diag-masked(-10)] == log(full unmasked row sum),
// so the main kernel needs no diagonal special-case.
__global__ __launch_bounds__(256) void norm_convert_kernel(
    const float* __restrict__ fq, const float* __restrict__ fk,
    uint16_t* __restrict__ qb, uint16_t* __restrict__ kb,
    float* __restrict__ lpT)
{
    const int wave = threadIdx.x >> 6;
    const int lane = threadIdx.x & 63;
    const int row  = blockIdx.x * 4 + wave;

    if (row < NROWS) {
        const float* qsrc = fq + (size_t)row * DDIM;
        const float* ksrc = fk + (size_t)row * DDIM;
        float4 vq = ((const float4*)qsrc)[lane];
        float4 vk = ((const float4*)ksrc)[lane];
        float ssq = vq.x*vq.x + vq.y*vq.y + vq.z*vq.z + vq.w*vq.w;
        float ssk = vk.x*vk.x + vk.y*vk.y + vk.z*vk.z + vk.w*vk.w;
        float dqk = vq.x*vk.x + vq.y*vk.y + vq.z*vk.z + vq.w*vk.w;
        #pragma unroll
        for (int m = 1; m < 64; m <<= 1) {
            ssq += __shfl_xor(ssq, m, 64);
            ssk += __shfl_xor(ssk, m, 64);
            dqk += __shfl_xor(dqk, m, 64);
        }
        float r = rsqrtf(ssq);
        ushort4 o;
        o.x = f2bf(vq.x * r); o.y = f2bf(vq.y * r); o.z = f2bf(vq.z * r); o.w = f2bf(vq.w * r);
        ((ushort4*)(qb + (size_t)row * DDIM))[lane] = o;
        if (lane == 0) {
            float denom = fmaxf(sqrtf(ssq) * sqrtf(ssk), 1e-8f);
            lpT[row] = (dqk / denom) * INV_T;
        }
    } else {
        const int r_ = row - NROWS;
        const float* src = fk + (size_t)r_ * DDIM;
        float4 v = ((const float4*)src)[lane];
        float ss = v.x*v.x + v.y*v.y + v.z*v.z + v.w*v.w;
        #pragma unroll
        for (int m = 1; m < 64; m <<= 1) ss += __shfl_xor(ss, m, 64);
        float r = rsqrtf(ss);
        ushort4 o;
        o.x = f2bf(v.x * r); o.y = f2bf(v.y * r); o.z = f2bf(v.z * r); o.w = f2bf(v.w * r);
        ((ushort4*)(kb + (size_t)r_ * DDIM))[lane] = o;
    }
}

// Kernel 2: round-12 skeleton (the reproducible 49.7-50.9us floor config)
// with ONE change: MFMA shape 16x16x32 -> 32x32x16. Rationale: across four
// structurally different schedules (R8/R9/R13/R14: lockstep/barrier-free,
// 1/2 trains, 9-20% occupancy, 160-288 MB DMA) time is pinned at ~3.0x the
// MFMA content -- the only conserved quantity is the MFMA instruction
// stream. 32x32x16 halves the instruction count (8 vs 16 per wave-chunk,
// same FLOP) and has a 15% higher measured ceiling (2382 vs 2075 TF).
// Fragment mapping (standard lane pattern, bench-verified vs reference):
//   A: row = lane&31, k = 8*(lane>>5)+j   B: col = lane&31, same k
//   C/D: col = lane&31, row = (reg&3) + 8*(reg>>2) + 4*(lane>>5)
// Swizzle positions collapse: A pos = c ^ lane31 (row==lane31 mod 32),
// B pos = c ^ ((lane31>>1)&3); both 2 lanes/4-bank-group per phase = free.
// Staging, drain-barrier train, diag-free epilogue: unchanged from R12.
__global__ __launch_bounds__(256, 2) void nce_main_kernel(
    const uint16_t* __restrict__ qb, const uint16_t* __restrict__ kb,
    float* __restrict__ gpl)
{
    __shared__ __align__(16) uint16_t lds_q[BM * DDIM];     // 65536 B, swizzled
    __shared__ __align__(16) uint16_t lds_k[2 * BN * 32];   // 16384 B, 2 bufs, swizzled

    const int tid    = threadIdx.x;
    const int wave   = tid >> 6;
    const int lane   = tid & 63;
    const int lane31 = lane & 31;
    const int half   = lane >> 5;       // k-half selector for A/B fragments
    const int wr     = wave >> 1;
    const int wc     = wave & 1;
    const int rowBase      = blockIdx.x * BM;
    const int colGroupBase = blockIdx.y * COLS_PER_GROUP;

    // ---- Stage Q tile once: 4096 chunks of 16B, 16 instrs/wave, source-swizzled.
    #pragma unroll
    for (int i = 0; i < 16; ++i) {
        int S   = (wave * 16 + i) * 64 + lane;          // lds chunk id
        int row = S >> 5;
        int ch  = (S & 31) ^ (row & 31);                // swizzle: source chunk
        async_copy16(qb + (size_t)(rowBase + row) * DDIM + ch * 8,
                     lds_q + (size_t)(wave * 16 + i) * 512);
    }

    // ---- K staging lane constants (chunk = 16B; 4 chunks per 32-col row).
    int kS0   = wave * 128 + lane;                      // i=0 chunk id in 512-chunk buffer
    int krow0 = kS0 >> 2;
    int kch0  = (lane & 3) ^ ((krow0 >> 1) & 3);        // proven source swizzle
    int krow1 = (kS0 + 64) >> 2;
    int kch1  = (lane & 3) ^ ((krow1 >> 1) & 3);
    const uint16_t* kbase0 = kb + (size_t)(colGroupBase + krow0) * DDIM + kch0 * 8;
    const uint16_t* kbase1 = kb + (size_t)(colGroupBase + krow1) * DDIM + kch1 * 8;
    uint16_t* kl0 = lds_k + wave * 1024;                // wave-uniform dest (i=0)

    // phase 0 (jt=0, kk=0) into buf 0
    async_copy16(kbase0, kl0);
    async_copy16(kbase1, kl0 + 512);
    __syncthreads();    // Q + first K chunk visible

    // ---- Fragment address constants.
    // A: per mt (2 row-blocks of 32), base row = wr*64 + mt*32 + lane31.
    int arow[2];
    #pragma unroll
    for (int mt = 0; mt < 2; ++mt) arow[mt] = (wr * 64 + mt * 32 + lane31) * 256;
    // B: per nt (2 col-blocks of 32), base = (wc*64 + nt*32 + lane31)*32.
    int brow[2];
    #pragma unroll
    for (int nt = 0; nt < 2; ++nt) brow[nt] = (wc * 64 + nt * 32 + lane31) * 32;
    const int bxor = (lane31 >> 1) & 3;                 // B swizzle term

    float l_run[32];
    #pragma unroll
    for (int i = 0; i < 32; ++i) l_run[i] = 0.f;

    for (int jt = 0; jt < 8; ++jt) {
        f32x16 acc[2][2];
        #pragma unroll
        for (int mt = 0; mt < 2; ++mt)
            #pragma unroll
            for (int nt = 0; nt < 2; ++nt)
                #pragma unroll
                for (int r = 0; r < 16; ++r)
                    acc[mt][nt][r] = 0.f;

        #pragma unroll
        for (int kk = 0; kk < 8; ++kk) {
            const int p    = (jt << 3) + kk;
            const int buf  = p & 1;
            const int nbuf = buf ^ 1;

            // Issue next chunk's loads (drained only at the NEXT barrier).
            if (p < 63) {
                int np  = p + 1;
                int off = ((np >> 3) << 15) + ((np & 7) << 5);  // njt*128*256 + nkk*32
                uint16_t* ld = lds_k + nbuf * 4096 + wave * 1024;
                async_copy16(kbase0 + off, ld);
                async_copy16(kbase1 + off, ld + 512);
            }

            // Fragments: A/B 16B chunk index c within the 32-k chunk =
            // kh*2 + half (8 bf16 per 16B). 4 A + 4 B ds_read_b128.
            bf16x8 av[2][2], bv[2][2];
            #pragma unroll
            for (int kh = 0; kh < 2; ++kh) {
                const int ca = ((kk << 2) + kh * 2 + half);
                #pragma unroll
                for (int mt = 0; mt < 2; ++mt)
                    av[mt][kh] = *(const bf16x8*)&lds_q[arow[mt] + ((ca ^ lane31) << 3)];
                const int cb = (kh * 2 + half) ^ bxor;
                #pragma unroll
                for (int nt = 0; nt < 2; ++nt)
                    bv[nt][kh] = *(const bf16x8*)&lds_k[buf * 4096 + brow[nt] + (cb << 3)];
            }
            #pragma unroll
            for (int kh = 0; kh < 2; ++kh)
                #pragma unroll
                for (int mt = 0; mt < 2; ++mt)
                    #pragma unroll
                    for (int nt = 0; nt < 2; ++nt)
                        acc[mt][nt] = __builtin_amdgcn_mfma_f32_32x32x16_bf16(
                            av[mt][kh], bv[nt][kh], acc[mt][nt], 0, 0, 0);

            __syncthreads();    // publish chunk p+1's writes / guard buf reuse
        }

        // Epilogue: fixed-max exp accumulate, full row, no diag special-case.
        // acc[mt][nt][r] is (row = (r&3)+8*(r>>2)+4*half within mt's 32-block,
        // col = lane31 within nt's 32-block); sum over nt here, cols later.
        #pragma unroll
        for (int mt = 0; mt < 2; ++mt)
            #pragma unroll
            for (int r = 0; r < 16; ++r) {
                float s = exp2f(fmaf(acc[mt][0][r], K1, -K1))
                        + exp2f(fmaf(acc[mt][1][r], K1, -K1));
                l_run[mt * 16 + r] += s;
            }
    }

    // Cross-lane reduce over the 32 cols (lanes within each 32-half share rows).
    #pragma unroll
    for (int i = 0; i < 32; ++i) {
        float v = l_run[i];
        v += __shfl_xor(v, 1, 64);
        v += __shfl_xor(v, 2, 64);
        v += __shfl_xor(v, 4, 64);
        v += __shfl_xor(v, 8, 64);
        v += __shfl_xor(v, 16, 64);     // stays within each 32-lane half
        l_run[i] = v;
    }
    // All LDS reads/writes done (last barrier passed; no loads in flight).
    float* pl = (float*)lds_k;      // 256 floats scratch
    if (lane31 == 0) {              // lanes 0 and 32 (their halves' rows)
        #pragma unroll
        for (int mt = 0; mt < 2; ++mt)
            #pragma unroll
            for (int r = 0; r < 16; ++r) {
                int lr = wr * 64 + mt * 32 + (r & 3) + 8 * (r >> 2) + 4 * half;
                pl[wc * 128 + lr] = l_run[mt * 16 + r];
            }
    }
    __syncthreads();
    if (tid < 128) {
        float L = pl[tid] + pl[128 + tid];
        gpl[(size_t)blockIdx.y * NROWS + rowBase + tid] = L;
    }
}

// Kernel 3: merge GJ partial sums; loss = M0 + log(L) - l_pos/T.
// (L already contains the diagonal = positive term; see kernel 1.)
__global__ __launch_bounds__(256) void finalize_kernel(
    const float* __restrict__ gpl, const float* __restrict__ lpT,
    float* __restrict__ out)
{
    int t = blockIdx.x * 256 + threadIdx.x;
    if (t >= NROWS) return;
    float L = 0.f;
    #pragma unroll
    for (int g = 0; g < GJ; ++g) L += gpl[g * NROWS + t];
    out[t] = INV_T + __logf(L) - lpT[t];
}

extern "C" void kernel_launch(void* const* d_in, const int* in_sizes, int n_in,
                              void* d_out, int out_size, void* d_ws, size_t ws_size,
                              hipStream_t stream) {
    const float* fq = (const float*)d_in[0];
    const float* fk = (const float*)d_in[1];
    char* ws = (char*)d_ws;
    // layout: qb 4MB | kb 4MB | lpT 32KB | gpl 256KB
    uint16_t* qb  = (uint16_t*)(ws);
    uint16_t* kb  = (uint16_t*)(ws + 4194304);
    float*    lpT = (float*)(ws + 8388608);
    float*    gpl = (float*)(ws + 8421376);

    norm_convert_kernel<<<(2 * NROWS) / 4, 256, 0, stream>>>(fq, fk, qb, kb, lpT);
    dim3 grid(NROWS / BM, GJ);
    nce_main_kernel<<<grid, 256, 0, stream>>>(qb, kb, gpl);
    finalize_kernel<<<NROWS / 256, 256, 0, stream>>>(gpl, lpT, (float*)d_out);
}

// Round 16
// 111.457 us; speedup vs baseline: 1.0157x; 1.0157x over previous
//
#include <hip/hip_runtime.h>
#include <stdint.h>
#include <math.h>

#define NROWS 8192
#define DDIM  256
#define BM    128
#define BN    128
#define GJ    8                         // column groups (grid.y)
#define COLS_PER_GROUP (NROWS / GJ)     // 1024

constexpr float INV_T  = 1.0f / 0.07f;  // fixed LSE max M0 = 1/T (|logit| <= 1/T)
constexpr float LOG2E  = 1.44269504f;
constexpr float K1     = INV_T * LOG2E; // exp2 arg: fma(acc, K1, -K1)

typedef __bf16 bf16x8 __attribute__((ext_vector_type(8)));
typedef float  f32x4  __attribute__((ext_vector_type(4)));

__device__ __forceinline__ void async_copy16(const uint16_t* g, uint16_t* l) {
    __builtin_amdgcn_global_load_lds(
        (const __attribute__((address_space(1))) uint32_t*)g,
        (__attribute__((address_space(3))) uint32_t*)l, 16, 0, 0);
}

__device__ inline uint16_t f2bf(float f) {
    uint32_t u = __float_as_uint(f);
    u += 0x7fffu + ((u >> 16) & 1u);    // RNE
    return (uint16_t)(u >> 16);
}

// Kernel 1: normalize rows to unit length (bf16 out). One wave per row.
// q-row waves ALSO compute l_pos = cos(q_i,k_i) in fp32 (validated rounds 6-15):
// LSE over [l_pos, row-with-diag-masked(-10)] == log(full unmasked row sum),
// so the main kernel needs no diagonal special-case.
__global__ __launch_bounds__(256) void norm_convert_kernel(
    const float* __restrict__ fq, const float* __restrict__ fk,
    uint16_t* __restrict__ qb, uint16_t* __restrict__ kb,
    float* __restrict__ lpT)
{
    const int wave = threadIdx.x >> 6;
    const int lane = threadIdx.x & 63;
    const int row  = blockIdx.x * 4 + wave;

    if (row < NROWS) {
        const float* qsrc = fq + (size_t)row * DDIM;
        const float* ksrc = fk + (size_t)row * DDIM;
        float4 vq = ((const float4*)qsrc)[lane];
        float4 vk = ((const float4*)ksrc)[lane];
        float ssq = vq.x*vq.x + vq.y*vq.y + vq.z*vq.z + vq.w*vq.w;
        float ssk = vk.x*vk.x + vk.y*vk.y + vk.z*vk.z + vk.w*vk.w;
        float dqk = vq.x*vk.x + vq.y*vk.y + vq.z*vk.z + vq.w*vk.w;
        #pragma unroll
        for (int m = 1; m < 64; m <<= 1) {
            ssq += __shfl_xor(ssq, m, 64);
            ssk += __shfl_xor(ssk, m, 64);
            dqk += __shfl_xor(dqk, m, 64);
        }
        float r = rsqrtf(ssq);
        ushort4 o;
        o.x = f2bf(vq.x * r); o.y = f2bf(vq.y * r); o.z = f2bf(vq.z * r); o.w = f2bf(vq.w * r);
        ((ushort4*)(qb + (size_t)row * DDIM))[lane] = o;
        if (lane == 0) {
            float denom = fmaxf(sqrtf(ssq) * sqrtf(ssk), 1e-8f);
            lpT[row] = (dqk / denom) * INV_T;
        }
    } else {
        const int r_ = row - NROWS;
        const float* src = fk + (size_t)r_ * DDIM;
        float4 v = ((const float4*)src)[lane];
        float ss = v.x*v.x + v.y*v.y + v.z*v.z + v.w*v.w;
        #pragma unroll
        for (int m = 1; m < 64; m <<= 1) ss += __shfl_xor(ss, m, 64);
        float r = rsqrtf(ss);
        ushort4 o;
        o.x = f2bf(v.x * r); o.y = f2bf(v.y * r); o.z = f2bf(v.z * r); o.w = f2bf(v.w * r);
        ((ushort4*)(kb + (size_t)r_ * DDIM))[lane] = o;
    }
}

// Kernel 2: the session's measured-best configuration (rounds 9/12,
// 49.7-50.9us reproducible). BM=128, 4 waves 2x2 (16 MFMA/chunk/wave),
// Q tile staged once in LDS (64KB), K double-buffered BK=32 via
// global_load_lds, one drain-barrier per chunk, measured-conflict-free
// source/read swizzles (SQ_LDS_BANK_CONFLICT = 0), diag-free fixed-max exp
// epilogue. Fifteen rounds across seven schedule families (counted-vmcnt
// rings, register FIFOs, barrier-free wave-private staging, A-streaming,
// merged trains, read-minimal dense-MFMA geometry, 32x32 MFMA shape)
// established a shape-/sync-/occupancy-independent floor at ~3x MFMA
// content for this op at HIP-source level; this config sits on it with the
// session's two real wins (swizzle fix, epilogue algebra) incorporated.
__global__ __launch_bounds__(256, 2) void nce_main_kernel(
    const uint16_t* __restrict__ qb, const uint16_t* __restrict__ kb,
    float* __restrict__ gpl)
{
    __shared__ __align__(16) uint16_t lds_q[BM * DDIM];     // 65536 B, swizzled
    __shared__ __align__(16) uint16_t lds_k[2 * BN * 32];   // 16384 B, 2 bufs, swizzled

    const int tid    = threadIdx.x;
    const int wave   = tid >> 6;
    const int lane   = tid & 63;
    const int quad   = lane >> 4;
    const int lanelo = lane & 15;
    const int wr     = wave >> 1;
    const int wc     = wave & 1;
    const int rowBase      = blockIdx.x * BM;
    const int colGroupBase = blockIdx.y * COLS_PER_GROUP;

    // ---- Stage Q tile once: 4096 chunks of 16B, 16 instrs/wave, source-swizzled.
    #pragma unroll
    for (int i = 0; i < 16; ++i) {
        int S   = (wave * 16 + i) * 64 + lane;          // lds chunk id
        int row = S >> 5;
        int ch  = (S & 31) ^ (row & 31);                // swizzle: source chunk
        async_copy16(qb + (size_t)(rowBase + row) * DDIM + ch * 8,
                     lds_q + (size_t)(wave * 16 + i) * 512);
    }

    // ---- K staging lane constants (chunk = 16B; 4 chunks per 32-col row).
    int kS0   = wave * 128 + lane;                      // i=0 chunk id in 512-chunk buffer
    int krow0 = kS0 >> 2;
    int kch0  = (lane & 3) ^ ((krow0 >> 1) & 3);        // proven source swizzle
    int krow1 = (kS0 + 64) >> 2;
    int kch1  = (lane & 3) ^ ((krow1 >> 1) & 3);
    const uint16_t* kbase0 = kb + (size_t)(colGroupBase + krow0) * DDIM + kch0 * 8;
    const uint16_t* kbase1 = kb + (size_t)(colGroupBase + krow1) * DDIM + kch1 * 8;
    uint16_t* kl0 = lds_k + wave * 1024;                // wave-uniform dest (i=0)

    // phase 0 (jt=0, kk=0) into buf 0
    async_copy16(kbase0, kl0);
    async_copy16(kbase1, kl0 + 512);
    __syncthreads();    // Q + first K chunk visible

    // ---- Fragment address constants.
    int rq[4], rq31[4];
    #pragma unroll
    for (int mt = 0; mt < 4; ++mt) {
        rq[mt]   = wr * 64 + mt * 16 + lanelo;
        rq31[mt] = rq[mt] & 31;
    }
    int bvoff[4];
    #pragma unroll
    for (int nt = 0; nt < 4; ++nt) {
        int rk = wc * 64 + nt * 16 + lanelo;
        bvoff[nt] = rk * 32 + (quad ^ ((lanelo >> 1) & 3)) * 8;  // proven read swizzle
    }

    float l_run[16];
    #pragma unroll
    for (int i = 0; i < 16; ++i) l_run[i] = 0.f;

    for (int jt = 0; jt < 8; ++jt) {
        f32x4 acc[4][4];
        #pragma unroll
        for (int mt = 0; mt < 4; ++mt)
            #pragma unroll
            for (int nt = 0; nt < 4; ++nt)
                acc[mt][nt] = (f32x4){0.f, 0.f, 0.f, 0.f};

        #pragma unroll
        for (int kk = 0; kk < 8; ++kk) {
            const int p    = (jt << 3) + kk;
            const int buf  = p & 1;
            const int nbuf = buf ^ 1;

            // Issue next chunk's loads (drained only at the NEXT barrier).
            if (p < 63) {
                int np  = p + 1;
                int off = ((np >> 3) << 15) + ((np & 7) << 5);  // njt*128*256 + nkk*32
                uint16_t* ld = lds_k + nbuf * 4096 + wave * 1024;
                async_copy16(kbase0 + off, ld);
                async_copy16(kbase1 + off, ld + 512);
            }

            // Compute on buf.
            bf16x8 av[4], bv[4];
            #pragma unroll
            for (int mt = 0; mt < 4; ++mt) {
                int chp = ((kk << 2) + quad) ^ rq31[mt];
                av[mt] = *(const bf16x8*)&lds_q[rq[mt] * 256 + chp * 8];
            }
            #pragma unroll
            for (int nt = 0; nt < 4; ++nt)
                bv[nt] = *(const bf16x8*)&lds_k[buf * 4096 + bvoff[nt]];
            #pragma unroll
            for (int mt = 0; mt < 4; ++mt)
                #pragma unroll
                for (int nt = 0; nt < 4; ++nt)
                    acc[mt][nt] = __builtin_amdgcn_mfma_f32_16x16x32_bf16(av[mt], bv[nt], acc[mt][nt], 0, 0, 0);

            __syncthreads();    // publish chunk p+1's writes / guard buf reuse
        }

        // Epilogue: fixed-max exp accumulate, full row, no diag special-case.
        #pragma unroll
        for (int mt = 0; mt < 4; ++mt) {
            #pragma unroll
            for (int rg = 0; rg < 4; ++rg) {
                float s = 0.f;
                #pragma unroll
                for (int nt = 0; nt < 4; ++nt)
                    s += exp2f(fmaf(acc[mt][nt][rg], K1, -K1));
                l_run[mt * 4 + rg] += s;
            }
        }
    }

    // Cross-lane reduce over the 16 lanelo lanes (same row, different cols).
    #pragma unroll
    for (int i = 0; i < 16; ++i) {
        float v = l_run[i];
        v += __shfl_xor(v, 1, 64);
        v += __shfl_xor(v, 2, 64);
        v += __shfl_xor(v, 4, 64);
        v += __shfl_xor(v, 8, 64);
        l_run[i] = v;
    }
    // All LDS reads/writes done (last barrier passed; no loads in flight).
    float* pl = (float*)lds_k;      // 256 floats scratch
    if (lanelo == 0) {
        #pragma unroll
        for (int mt = 0; mt < 4; ++mt)
            #pragma unroll
            for (int rg = 0; rg < 4; ++rg) {
                int lr = wr * 64 + mt * 16 + quad * 4 + rg;
                pl[wc * 128 + lr] = l_run[mt * 4 + rg];
            }
    }
    __syncthreads();
    if (tid < 128) {
        float L = pl[tid] + pl[128 + tid];
        gpl[(size_t)blockIdx.y * NROWS + rowBase + tid] = L;
    }
}

// Kernel 3: merge GJ partial sums; loss = M0 + log(L) - l_pos/T.
// (L already contains the diagonal = positive term; see kernel 1.)
__global__ __launch_bounds__(256) void finalize_kernel(
    const float* __restrict__ gpl, const float* __restrict__ lpT,
    float* __restrict__ out)
{
    int t = blockIdx.x * 256 + threadIdx.x;
    if (t >= NROWS) return;
    float L = 0.f;
    #pragma unroll
    for (int g = 0; g < GJ; ++g) L += gpl[g * NROWS + t];
    out[t] = INV_T + __logf(L) - lpT[t];
}

extern "C" void kernel_launch(void* const* d_in, const int* in_sizes, int n_in,
                              void* d_out, int out_size, void* d_ws, size_t ws_size,
                              hipStream_t stream) {
    const float* fq = (const float*)d_in[0];
    const float* fk = (const float*)d_in[1];
    char* ws = (char*)d_ws;
    // layout: qb 4MB | kb 4MB | lpT 32KB | gpl 256KB
    uint16_t* qb  = (uint16_t*)(ws);
    uint16_t* kb  = (uint16_t*)(ws + 4194304);
    float*    lpT = (float*)(ws + 8388608);
    float*    gpl = (float*)(ws + 8421376);

    norm_convert_kernel<<<(2 * NROWS) / 4, 256, 0, stream>>>(fq, fk, qb, kb, lpT);
    dim3 grid(NROWS / BM, GJ);
    nce_main_kernel<<<grid, 256, 0, stream>>>(qb, kb, gpl);
    finalize_kernel<<<NROWS / 256, 256, 0, stream>>>(gpl, lpT, (float*)d_out);
}